// Round 4
// baseline (638.432 us; speedup 1.0000x reference)
//
#include <hip/hip_runtime.h>

typedef __bf16 bf16;
typedef __bf16 bf16x8 __attribute__((ext_vector_type(8)));
typedef __bf16 bf16x4 __attribute__((ext_vector_type(4)));
typedef __bf16 bf16x2 __attribute__((ext_vector_type(2)));
typedef float floatx4 __attribute__((ext_vector_type(4)));
typedef float floatx16 __attribute__((ext_vector_type(16)));

#define NB 4
#define NT 2048
#define NC 2048
#define NH 16
#define ND 128
#define QKS 4096   // qk row stride (Q cols 0..2047, K cols 2048..4095)

__device__ __forceinline__ void load_lds16(const void* gptr, void* ldsptr) {
  __builtin_amdgcn_global_load_lds(
      (const __attribute__((address_space(1))) unsigned int*)gptr,
      (__attribute__((address_space(3))) unsigned int*)ldsptr, 16, 0, 0);
}

__device__ __forceinline__ unsigned pack2(float a, float b) {
  bf16x2 v;
  v[0] = (bf16)a; v[1] = (bf16)b;
  return __builtin_bit_cast(unsigned, v);
}

// ---------------- cast fp32 -> bf16 (4 elts/thread) ----------------
__global__ __launch_bounds__(256) void cast_f32_bf16(const float* __restrict__ in,
                                                     bf16* __restrict__ out) {
  const int i = blockIdx.x * 256 + threadIdx.x;
  const float4 v = ((const float4*)in)[i];
  bf16x4 o;
  o[0] = (bf16)v.x; o[1] = (bf16)v.y; o[2] = (bf16)v.z; o[3] = (bf16)v.w;
  ((bf16x4*)out)[i] = o;
}

// ------ transpose+cast: in[R][Cc] f32 -> out[Cc][R] bf16, 128r x 64c tiles ------
__global__ __launch_bounds__(256) void transpose_cast(const float* __restrict__ in,
                                                      bf16* __restrict__ out,
                                                      int R, int Cc) {
  __shared__ float tile[128][65];
  const int r0 = blockIdx.y * 128, c0 = blockIdx.x * 64;
  const int rr = threadIdx.x >> 6, cc = threadIdx.x & 63;
#pragma unroll
  for (int i = 0; i < 32; ++i)
    tile[rr + i * 4][cc] = in[(size_t)(r0 + rr + i * 4) * Cc + c0 + cc];
  __syncthreads();
  const int rv = threadIdx.x & 63, halfr = (threadIdx.x >> 6) & 1, crh = threadIdx.x >> 7;
#pragma unroll
  for (int i = 0; i < 32; ++i) {
    const int cr = crh * 32 + i;
    out[(size_t)(c0 + cr) * R + r0 + halfr * 64 + rv] = (bf16)tile[halfr * 64 + rv][cr];
  }
}

// ------------- GEMM: C[M][N] = A[M][K]*Bt[N][K]^T.
//   256x256 tile, BK=64, 8 waves (2Mx4N), 512 thr, 128KiB double-buffered LDS.
//   32x32x16 MFMA core (2495 TF ceiling vs 2075 for 16x16x32 — ~17% less pipe
//   time, identical fragment/read counts so the proven schedule is unchanged):
//     p<3 : issue next-m-sub A reads(4); [stage t+1: B@p0, A@p1]; bar; lgkm(4); 8 MFMA; bar
//     p==3: vmcnt(0); bar; read A-sub0(t+1)(4); lgkm(4); 8 MFMA; read B(t+1)(8); bar
//   Staging source addresses hoisted: per-lane 64b pointers advanced +64/tile.
//   EPI==0: plain store to C.  EPI==1: fused RoPE (Q/K) + V-transpose epilogue.
template <int EPI, typename OutT>
__global__ __launch_bounds__(512, 2) void gemm_bt(const bf16* __restrict__ A,
                                                  const bf16* __restrict__ Bt,
                                                  OutT* __restrict__ C,
                                                  bf16* __restrict__ qk,
                                                  bf16* __restrict__ vt,
                                                  int M, int N, int K, int NTX) {
  // buf b: As at b*32768, Bs at b*32768+16384 (elems). 131072 B total.
  __shared__ bf16 smem[65536];
  __shared__ float invf_s[64];
  const int tid = threadIdx.x;
  const int w = tid >> 6, l = tid & 63, l32 = l & 31, hi = l >> 5;
  const int wm = w >> 2, wn = w & 3;      // 2 M-waves x 4 N-waves

  // XCD-bijective remap (gridDim.x % 8 == 0) then 8-M-tile band swizzle
  const int cpx = gridDim.x >> 3;
  const int orig = blockIdx.x;
  const int wgid = (orig & 7) * cpx + (orig >> 3);
  const int per = 8 * NTX;
  const int band = wgid / per, rem = wgid - band * per;
  const int by = band * 8 + (rem & 7), bx = rem >> 3;
  const int m0 = by * 256, n0 = bx * 256;

  if (EPI == 1 && tid < 64)
    invf_s[tid] = exp2f(-(float)tid * 0.20762050593046014f);  // 10000^(-d/64)

  const int KT = K >> 6;

  // 32x32x16 fragment LDS offsets (elements), constant per thread.
  //   A-operand lane map: row = l32 (+ wm*128 + p*32), k-chunk = ks*2 + hi
  //   swizzled slot = (ks*2 + hi) ^ (row & 7), row&7 == l32&7 for all frags.
  const int sw = l32 & 7;
  int aoff[4], boff[2][4];
#pragma unroll
  for (int ks = 0; ks < 4; ++ks) {
    aoff[ks] = (wm * 128 + l32) * 64 + (((ks * 2 + hi) ^ sw) * 8);
#pragma unroll
    for (int ns = 0; ns < 2; ++ns)
      boff[ns][ks] = (wn * 64 + ns * 32 + l32) * 64 + (((ks * 2 + hi) ^ sw) * 8);
  }

  floatx16 acc[4][2];
#pragma unroll
  for (int i = 0; i < 4; ++i)
#pragma unroll
    for (int j = 0; j < 2; ++j)
#pragma unroll
      for (int r = 0; r < 16; ++r) acc[i][j][r] = 0.f;

  bf16x8 af[2][4];    // [m-sub parity][ks] A frags, ping-pong
  bf16x8 bfr[2][4];   // [ns][ks] B frags — reused across tiles

  // Hoisted per-lane staging sources (4 A + 4 B gloads per wave per tile) and
  // wave-uniform LDS chunk bases.
  const bf16* a_src[4];
  const bf16* b_src[4];
  int ldsoff[4];
#pragma unroll
  for (int j = 0; j < 4; ++j) {
    const int h = j >> 1, i = j & 1;
    const int fb = h * 1024 + w * 128 + i * 64;   // wave-uniform chunk base
    const int f = fb + l;
    const int r = f >> 3, cs = f & 7, c = cs ^ (r & 7);
    ldsoff[j] = fb * 8;
    a_src[j] = A + (size_t)(m0 + r) * K + c * 8;
    b_src[j] = Bt + (size_t)(n0 + r) * K + c * 8;
  }

  // ---- prologue: stage tile0, drain, barrier, pre-read m-sub0 + B of tile0 ----
  {
#pragma unroll
    for (int j = 0; j < 4; ++j) load_lds16(a_src[j], smem + ldsoff[j]);
#pragma unroll
    for (int j = 0; j < 4; ++j) load_lds16(b_src[j], smem + 16384 + ldsoff[j]);
#pragma unroll
    for (int j = 0; j < 4; ++j) { a_src[j] += 64; b_src[j] += 64; }
    asm volatile("s_waitcnt vmcnt(0)" ::: "memory");
    __builtin_amdgcn_sched_barrier(0);
    __builtin_amdgcn_s_barrier();
    __builtin_amdgcn_sched_barrier(0);
#pragma unroll
    for (int ks = 0; ks < 4; ++ks) af[0][ks] = *(const bf16x8*)(smem + aoff[ks]);
#pragma unroll
    for (int ns = 0; ns < 2; ++ns)
#pragma unroll
      for (int ks = 0; ks < 4; ++ks)
        bfr[ns][ks] = *(const bf16x8*)(smem + 16384 + boff[ns][ks]);
  }

#pragma unroll 1
  for (int t = 0; t < KT; ++t) {
    bf16* cur = smem + ((t & 1) << 15);
    bf16* nxt = smem + (((t + 1) & 1) << 15);

#pragma unroll
    for (int p = 0; p < 4; ++p) {
      if (p < 3) {
        // --- read-ahead A m-sub (p+1) of this tile ---
#pragma unroll
        for (int ks = 0; ks < 4; ++ks)
          af[(p + 1) & 1][ks] =
              *(const bf16x8*)(cur + aoff[ks] + (p + 1) * 2048);
        // --- stage tile t+1 (B halves in p0, A halves in p1) ---
        if (p == 0 && t + 1 < KT) {
#pragma unroll
          for (int j = 0; j < 4; ++j) load_lds16(b_src[j], nxt + 16384 + ldsoff[j]);
#pragma unroll
          for (int j = 0; j < 4; ++j) b_src[j] += 64;
        }
        if (p == 1 && t + 1 < KT) {
#pragma unroll
          for (int j = 0; j < 4; ++j) load_lds16(a_src[j], nxt + ldsoff[j]);
#pragma unroll
          for (int j = 0; j < 4; ++j) a_src[j] += 64;
        }
        __builtin_amdgcn_sched_barrier(0);
        __builtin_amdgcn_s_barrier();
        // drain this phase's frags (read one cluster ago); keep the 4 just issued
        asm volatile("s_waitcnt lgkmcnt(4)" ::: "memory");
        __builtin_amdgcn_sched_barrier(0);
      } else {
        // --- boundary: own staging of t+1 landed; barrier makes it visible ---
        asm volatile("s_waitcnt vmcnt(0)" ::: "memory");
        __builtin_amdgcn_sched_barrier(0);
        __builtin_amdgcn_s_barrier();
        __builtin_amdgcn_sched_barrier(0);
        if (t + 1 < KT) {
          // read-ahead A m-sub0 of tile t+1
#pragma unroll
          for (int ks = 0; ks < 4; ++ks)
            af[0][ks] = *(const bf16x8*)(nxt + aoff[ks]);
          asm volatile("s_waitcnt lgkmcnt(4)" ::: "memory");   // drains p3's reads
        } else {
          asm volatile("s_waitcnt lgkmcnt(0)" ::: "memory");
        }
        __builtin_amdgcn_sched_barrier(0);
      }

      __builtin_amdgcn_s_setprio(1);
#pragma unroll
      for (int ks = 0; ks < 4; ++ks)
#pragma unroll
        for (int ns = 0; ns < 2; ++ns)
          acc[p][ns] = __builtin_amdgcn_mfma_f32_32x32x16_bf16(
              af[p & 1][ks], bfr[ns][ks], acc[p][ns], 0, 0, 0);
      __builtin_amdgcn_s_setprio(0);
      __builtin_amdgcn_sched_barrier(0);

      if (p == 3 && t + 1 < KT) {
        // read tile t+1's B frags while p3's MFMAs drain (old B fully consumed;
        // next p0's lgkm(4) drains these before first use)
#pragma unroll
        for (int ns = 0; ns < 2; ++ns)
#pragma unroll
          for (int ks = 0; ks < 4; ++ks)
            bfr[ns][ks] = *(const bf16x8*)(nxt + 16384 + boff[ns][ks]);
        __builtin_amdgcn_sched_barrier(0);
      }
      __builtin_amdgcn_s_barrier();
    }
  }

  // 32x32 C/D layout: col = l&31, row = (r&3) + 8*(r>>2) + 4*hi
  if constexpr (EPI == 0) {
#pragma unroll
    for (int ms = 0; ms < 4; ++ms)
#pragma unroll
      for (int ns = 0; ns < 2; ++ns) {
        const int col = n0 + wn * 64 + ns * 32 + l32;
#pragma unroll
        for (int r = 0; r < 16; ++r) {
          const int row = m0 + wm * 128 + ms * 32 + (r & 3) + 8 * (r >> 2) + 4 * hi;
          C[(size_t)row * N + col] = (OutT)acc[ms][ns][r];
        }
      }
  } else {
    // ---- fused epilogue: 2 rounds; round q stages quadrants (wm,q) of the
    //      256x256 tile as two 128x130 LDS tiles, then 256 threads/tile apply
    //      RoPE (Q/K cols) or transpose (V cols). All staging already drained.
    bf16* Tl = smem;
#pragma unroll 1
    for (int q = 0; q < 2; ++q) {
      if ((wn >> 1) == q) {
        bf16* Tg = Tl + wm * (128 * 130);
#pragma unroll
        for (int ms = 0; ms < 4; ++ms)
#pragma unroll
          for (int ns = 0; ns < 2; ++ns) {
            const int cl = (wn & 1) * 64 + ns * 32 + l32;
#pragma unroll
            for (int r = 0; r < 16; ++r) {
              const int rl = ms * 32 + (r & 3) + 8 * (r >> 2) + 4 * hi;
              Tg[rl * 130 + cl] = (bf16)acc[ms][ns][r];
            }
          }
      }
      __syncthreads();

      const int g = tid >> 8, t8 = tid & 255;      // group g handles quadrant (g,q)
      const int m0q = m0 + g * 128, n0q = n0 + q * 128;
      bf16* Tq = Tl + g * (128 * 130);
      const int nt = n0q >> 7;
      if (nt < 32) {
        // ---- Q or K quadrant: apply RoPE, store to qk[(m0q+r)][n0q + c] ----
        const int r = t8 >> 1, hd = t8 & 1;
        const float tt = (float)((m0q & (NT - 1)) + r);
        bf16* dst = qk + (size_t)(m0q + r) * QKS + n0q;
#pragma unroll
        for (int j8 = 0; j8 < 2; ++j8) {
          const int d0 = hd * 32 + j8 * 16;
          bf16x8 lo[2], hi2[2];
#pragma unroll
          for (int half8 = 0; half8 < 2; ++half8) {
#pragma unroll
            for (int jj = 0; jj < 8; ++jj) {
              const int d = d0 + half8 * 8 + jj;
              const float x1 = (float)Tq[r * 130 + d];
              const float x2 = (float)Tq[r * 130 + d + 64];
              float s, c;
              __sincosf(tt * invf_s[d], &s, &c);
              lo[half8][jj] = (bf16)(x1 * c - x2 * s);
              hi2[half8][jj] = (bf16)(x2 * c + x1 * s);
            }
            *(bf16x8*)(dst + d0 + half8 * 8) = lo[half8];
            *(bf16x8*)(dst + d0 + half8 * 8 + 64) = hi2[half8];
          }
        }
      } else {
        // ---- V quadrant: transpose into vt[(b*16+h)*128 + d][t] ----
        const int h = nt - 32;
        const int b = m0q >> 11;          // quadrant never straddles batch
        const int t0 = m0q & (NT - 1);
        const int vbase = (b * NH + h) * ND;
#pragma unroll
        for (int ii = 0; ii < 8; ++ii) {
          const int dd = (t8 >> 4) + ii * 16;
          const int ch = t8 & 15;
          bf16x8 o;
#pragma unroll
          for (int j = 0; j < 8; ++j) o[j] = Tq[(ch * 8 + j) * 130 + dd];
          *(bf16x8*)(vt + (size_t)(vbase + dd) * NT + t0 + ch * 8) = o;
        }
      }
      __syncthreads();
    }
  }
}

// ------------- flash attention: 32x32 MFMA, S^T/O^T orientation,
//               double-buffered K/V LDS, paired q-tiles for load balance ------
__global__ __launch_bounds__(256) void attn_kernel(const bf16* __restrict__ qk,
                                                   const bf16* __restrict__ vt,
                                                   bf16* __restrict__ y) {
  __shared__ bf16 Ks[2][64 * 128];   // [buf][kv][d]  xor-swizzled 16B chunks
  __shared__ bf16 Vs[2][128 * 64];   // [buf][d][kv]  xor-swizzled 16B chunks

  const int pair = blockIdx.x, h = blockIdx.y, b = blockIdx.z;
  const int tid = threadIdx.x;
  const int w = tid >> 6, l = tid & 63, half = l >> 5, l32 = l & 31;
  const float SCL = 0.08838834764831845f * 1.4426950408889634f;  // 1/sqrt(128)*log2(e)

#pragma unroll 1
  for (int pi = 0; pi < 2; ++pi) {
    const int qt = pi ? (15 - pair) : pair;
    const int q0 = qt * 128;
    const int ntiles = qt * 2 + 2;
    const int qg = q0 + w * 32 + l32;   // this lane's q row

    // Q B-fragments from global (RoPE'd): Q[q=l32][d = ks*16 + half*8 + j]
    bf16x8 aq[8];
#pragma unroll
    for (int ks = 0; ks < 8; ++ks)
      aq[ks] = *(const bf16x8*)(qk + (size_t)(b * NT + qg) * QKS + h * ND + ks * 16 + half * 8);

    floatx16 acc[4];
#pragma unroll
    for (int ni = 0; ni < 4; ++ni)
#pragma unroll
      for (int r = 0; r < 16; ++r) acc[ni][r] = 0.f;
    float mold = -3.0e38f, lsum = 0.f;

    // ---- stage tile 0 into buffer 0 ----
    {
#pragma unroll
      for (int i = 0; i < 4; ++i) {
        const int fb = i * 256 + w * 64, f = fb + l;
        { const int r = f >> 4, cs = f & 15, c = cs ^ (r & 15);
          load_lds16(qk + (size_t)(b * NT + r) * QKS + NC + h * ND + c * 8, &Ks[0][fb * 8]); }
        { const int r = f >> 3, cs = f & 7, c = cs ^ (r & 7);
          load_lds16(vt + ((size_t)((b * NH + h) * ND + r)) * NT + c * 8, &Vs[0][fb * 8]); }
      }
    }

#pragma unroll 1
    for (int it = 0; it < ntiles; ++it) {
      const int kv0 = it * 64;
      const int buf = it & 1;
      __syncthreads();   // drains loads for tile it; all waves done reading buf^1

      if (it + 1 < ntiles) {  // prefetch tile it+1 into the other buffer
        const int kvn = kv0 + 64, nb = buf ^ 1;
#pragma unroll
        for (int i = 0; i < 4; ++i) {
          const int fb = i * 256 + w * 64, f = fb + l;
          { const int r = f >> 4, cs = f & 15, c = cs ^ (r & 15);
            load_lds16(qk + (size_t)(b * NT + kvn + r) * QKS + NC + h * ND + c * 8, &Ks[nb][fb * 8]); }
          { const int r = f >> 3, cs = f & 7, c = cs ^ (r & 7);
            load_lds16(vt + ((size_t)((b * NH + h) * ND + r)) * NT + kvn + c * 8, &Vs[nb][fb * 8]); }
        }
      }

      if (kv0 <= q0 + w * 32 + 31) {  // wave has at least one unmasked kv
        // ---- S^T = K Q^T  (C: kv = (r&3)+8*(r>>2)+4*half, q = l32) ----
        floatx16 st[2];
#pragma unroll
        for (int ki = 0; ki < 2; ++ki)
#pragma unroll
          for (int r = 0; r < 16; ++r) st[ki][r] = 0.f;
#pragma unroll
        for (int ks = 0; ks < 8; ++ks) {
          const int slot = (ks * 2 + half) ^ (l32 & 15);
#pragma unroll
          for (int ki = 0; ki < 2; ++ki) {
            const bf16x8 ak = *(const bf16x8*)(&Ks[buf][(ki * 32 + l32) * 128 + slot * 8]);
            st[ki] = __builtin_amdgcn_mfma_f32_32x32x16_bf16(ak, aq[ks], st[ki], 0, 0, 0);
          }
        }

        // ---- mask + scale + row max (in-lane 32 + one shfl) ----
        float mx = -3.0e38f;
        if (kv0 + 63 > q0 + w * 32) {
#pragma unroll
          for (int ki = 0; ki < 2; ++ki)
#pragma unroll
            for (int r = 0; r < 16; ++r) {
              const int kg = kv0 + ki * 32 + (r & 3) + 8 * (r >> 2) + 4 * half;
              float s = st[ki][r] * SCL;
              s = (kg > qg) ? -3.0e38f : s;
              st[ki][r] = s;
              mx = fmaxf(mx, s);
            }
        } else {
#pragma unroll
          for (int ki = 0; ki < 2; ++ki)
#pragma unroll
            for (int r = 0; r < 16; ++r) {
              const float s = st[ki][r] * SCL;
              st[ki][r] = s;
              mx = fmaxf(mx, s);
            }
        }
        mx = fmaxf(mx, __shfl_xor(mx, 32));

        // ---- online softmax (log2 domain) ----
        const float mnew = fmaxf(mold, mx);
        const float al = exp2f(mold - mnew);
        float rs = 0.f;
#pragma unroll
        for (int ki = 0; ki < 2; ++ki)
#pragma unroll
          for (int r = 0; r < 16; ++r) {
            const float p = exp2f(st[ki][r] - mnew);
            st[ki][r] = p;
            rs += p;
          }
        rs += __shfl_xor(rs, 32);
        lsum = lsum * al + rs;
        mold = mnew;
#pragma unroll
        for (int ni = 0; ni < 4; ++ni)
#pragma unroll
          for (int r = 0; r < 16; ++r) acc[ni][r] *= al;

        // ---- repack P (C-layout) -> B-operand, in-register (16 shfl_xor32) ----
        unsigned pk[2][8];
#pragma unroll
        for (int ki = 0; ki < 2; ++ki)
#pragma unroll
          for (int d = 0; d < 8; ++d)
            pk[ki][d] = pack2(st[ki][2 * d], st[ki][2 * d + 1]);
        bf16x8 bp[4];
#pragma unroll
        for (int s = 0; s < 4; ++s) {
          const int ki = s >> 1, o = (s & 1) * 4;
          const unsigned a0 = pk[ki][o], a1 = pk[ki][o + 1], a2 = pk[ki][o + 2], a3 = pk[ki][o + 3];
          const unsigned s0 = (unsigned)__shfl_xor((int)a0, 32);
          const unsigned s1 = (unsigned)__shfl_xor((int)a1, 32);
          const unsigned s2 = (unsigned)__shfl_xor((int)a2, 32);
          const unsigned s3 = (unsigned)__shfl_xor((int)a3, 32);
          uint4 dw;
          dw.x = half ? s2 : a0;
          dw.y = half ? s3 : a1;
          dw.z = half ? a2 : s0;
          dw.w = half ? a3 : s1;
          bp[s] = __builtin_bit_cast(bf16x8, dw);
        }

        // ---- O^T += V^T P^T  (A = V^T rows, B = P) ----
#pragma unroll
        for (int ni = 0; ni < 4; ++ni) {
          const int rv = ni * 32 + l32;
#pragma unroll
          for (int s = 0; s < 4; ++s) {
            const int slot = (s * 2 + half) ^ (l32 & 7);
            const bf16x8 av = *(const bf16x8*)(&Vs[buf][rv * 64 + slot * 8]);
            acc[ni] = __builtin_amdgcn_mfma_f32_32x32x16_bf16(av, bp[s], acc[ni], 0, 0, 0);
          }
        }
      }
    }

    // ---- epilogue: O^T lane holds (d = ni*32+8*rg+4*half+j, q = l32) ----
    const float inv = 1.f / lsum;
    const size_t orow = (size_t)(b * NT + qg) * NC + h * ND;
#pragma unroll
    for (int ni = 0; ni < 4; ++ni)
#pragma unroll
      for (int rg = 0; rg < 4; ++rg) {
        bf16x4 o;
#pragma unroll
        for (int j = 0; j < 4; ++j) o[j] = (bf16)(acc[ni][rg * 4 + j] * inv);
        *(bf16x4*)(y + orow + ni * 32 + rg * 8 + half * 4) = o;
      }
    __syncthreads();  // protect K/V buffers before next sub-tile overwrites
  }
}

extern "C" void kernel_launch(void* const* d_in, const int* in_sizes, int n_in,
                              void* d_out, int out_size, void* d_ws, size_t ws_size,
                              hipStream_t stream) {
  const float* x      = (const float*)d_in[0];  // (4,2048,2048)
  const float* w_attn = (const float*)d_in[1];  // (2048,6144)
  const float* w_proj = (const float*)d_in[2];  // (2048,2048)
  float* out = (float*)d_out;
  char* ws = (char*)d_ws;

  // workspace layout: total 176,160,768 B (same proven footprint)
  bf16* qk  = (bf16*)(ws);                 // [8192][4096] RoPE'd Q|K   67,108,864 B
  bf16* vt  = (bf16*)(ws + 67108864);      // [4*16*128][2048] V^T      33,554,432 B
  bf16* xb  = (bf16*)(ws + 100663296);     // [8192][2048]              33,554,432 B
  bf16* wab = (bf16*)(ws + 134217728);     // [6144][2048]              25,165,824 B
  bf16* y   = wab;                         // aliases wab (dead after GEMM1)
  bf16* wpb = (bf16*)(ws + 167772160);     // [2048][2048]               8,388,608 B

  cast_f32_bf16<<<dim3(16384), dim3(256), 0, stream>>>(x, xb);
  transpose_cast<<<dim3(96, 16), dim3(256), 0, stream>>>(w_attn, wab, 2048, 6144);
  transpose_cast<<<dim3(32, 16), dim3(256), 0, stream>>>(w_proj, wpb, 2048, 2048);
  gemm_bt<1, float><<<dim3(768), dim3(512), 0, stream>>>(xb, wab, (float*)nullptr, qk, vt,
                                                         8192, 6144, 2048, 24);
  attn_kernel<<<dim3(8, 16, 4), dim3(256), 0, stream>>>(qk, vt, y);
  gemm_bt<0, float><<<dim3(256), dim3(512), 0, stream>>>(y, wpb, out, nullptr, nullptr,
                                                         8192, 2048, 2048, 8);
}

// Round 5
// 598.161 us; speedup vs baseline: 1.0673x; 1.0673x over previous
//
#include <hip/hip_runtime.h>

typedef __bf16 bf16;
typedef __bf16 bf16x8 __attribute__((ext_vector_type(8)));
typedef __bf16 bf16x4 __attribute__((ext_vector_type(4)));
typedef __bf16 bf16x2 __attribute__((ext_vector_type(2)));
typedef float floatx4 __attribute__((ext_vector_type(4)));
typedef float floatx16 __attribute__((ext_vector_type(16)));

#define NB 4
#define NT 2048
#define NC 2048
#define NH 16
#define ND 128
#define QKS 4096   // qk row stride (Q cols 0..2047, K cols 2048..4095)

__device__ __forceinline__ void load_lds16(const void* gptr, void* ldsptr) {
  __builtin_amdgcn_global_load_lds(
      (const __attribute__((address_space(1))) unsigned int*)gptr,
      (__attribute__((address_space(3))) unsigned int*)ldsptr, 16, 0, 0);
}

__device__ __forceinline__ unsigned pack2(float a, float b) {
  bf16x2 v;
  v[0] = (bf16)a; v[1] = (bf16)b;
  return __builtin_bit_cast(unsigned, v);
}

// ---------------- cast fp32 -> bf16 (4 elts/thread) ----------------
__global__ __launch_bounds__(256) void cast_f32_bf16(const float* __restrict__ in,
                                                     bf16* __restrict__ out) {
  const int i = blockIdx.x * 256 + threadIdx.x;
  const float4 v = ((const float4*)in)[i];
  bf16x4 o;
  o[0] = (bf16)v.x; o[1] = (bf16)v.y; o[2] = (bf16)v.z; o[3] = (bf16)v.w;
  ((bf16x4*)out)[i] = o;
}

// ------ transpose+cast: in[R][Cc] f32 -> out[Cc][R] bf16, 128r x 64c tiles ------
__global__ __launch_bounds__(256) void transpose_cast(const float* __restrict__ in,
                                                      bf16* __restrict__ out,
                                                      int R, int Cc) {
  __shared__ float tile[128][65];
  const int r0 = blockIdx.y * 128, c0 = blockIdx.x * 64;
  const int rr = threadIdx.x >> 6, cc = threadIdx.x & 63;
#pragma unroll
  for (int i = 0; i < 32; ++i)
    tile[rr + i * 4][cc] = in[(size_t)(r0 + rr + i * 4) * Cc + c0 + cc];
  __syncthreads();
  const int rv = threadIdx.x & 63, halfr = (threadIdx.x >> 6) & 1, crh = threadIdx.x >> 7;
#pragma unroll
  for (int i = 0; i < 32; ++i) {
    const int cr = crh * 32 + i;
    out[(size_t)(c0 + cr) * R + r0 + halfr * 64 + rv] = (bf16)tile[halfr * 64 + rv][cr];
  }
}

// stage one half-tile (128 rows x 64 cols) of a 256x64 K-panel into LDS.
// LDS dest linear in flat 16B-chunk id; global source pre-swizzled so that
// LDS chunk (r, cs) holds source chunk cs^(r&7) (same swizzle the frag reads undo).
// 2 global_load_lds per wave per call.
__device__ __forceinline__ void stage_half(bf16* lds, const bf16* __restrict__ g,
                                           int row0, int k0, int h, int K,
                                           int w, int l) {
#pragma unroll
  for (int i = 0; i < 2; ++i) {
    const int fb = h * 1024 + w * 128 + i * 64;   // wave-uniform chunk base
    const int f = fb + l;
    const int r = f >> 3, cs = f & 7, c = cs ^ (r & 7);
    load_lds16(g + (size_t)(row0 + r) * K + k0 + c * 8, lds + fb * 8);
  }
}

// ------------- GEMM: C[M][N] = A[M][K]*Bt[N][K]^T.  (reverted to the r2-bench
//   version — 16x16x32 core, 226.9 µs measured; 32x32 core regressed via 6.5x
//   LDS bank conflicts.)
//   256x256 tile, BK=64, 8 waves (2Mx4N), 512 thr, 128KiB double-buffered LDS.
//   4 phases/K-tile, 8 barriers/K-tile:
//     p0: ds_read B(8) + A-q0 + A-q1; stage t+1 B halves; bar; lgkm(4); MFMA q0; bar
//     p1: ds_read A-q2;              stage t+1 A halves; bar; lgkm(4); MFMA q1; bar
//     p2: ds_read A-q3;                                  bar; lgkm(4); MFMA q2; bar
//     p3: (no reads)                                     bar; lgkm(0); MFMA q3; vmcnt(0); bar
//   EPI==0: plain store to C.  EPI==1: fused RoPE (Q/K) + V-transpose epilogue.
template <int EPI, typename OutT>
__global__ __launch_bounds__(512, 2) void gemm_bt(const bf16* __restrict__ A,
                                                  const bf16* __restrict__ Bt,
                                                  OutT* __restrict__ C,
                                                  bf16* __restrict__ qk,
                                                  bf16* __restrict__ vt,
                                                  int M, int N, int K, int NTX) {
  // buf b: As at b*32768, Bs at b*32768+16384 (elems). 131072 B total.
  __shared__ bf16 smem[65536];
  __shared__ float invf_s[64];
  const int tid = threadIdx.x;
  const int w = tid >> 6, l = tid & 63, quad = l >> 4, l16 = l & 15;
  const int wm = w >> 2, wn = w & 3;      // 2 M-waves x 4 N-waves

  // XCD-bijective remap (gridDim.x % 8 == 0) then 8-M-tile band swizzle
  const int cpx = gridDim.x >> 3;
  const int orig = blockIdx.x;
  const int wgid = (orig & 7) * cpx + (orig >> 3);
  const int per = 8 * NTX;
  const int band = wgid / per, rem = wgid - band * per;
  const int by = band * 8 + (rem & 7), bx = rem >> 3;
  const int m0 = by * 256, n0 = bx * 256;

  if (EPI == 1 && tid < 64)
    invf_s[tid] = exp2f(-(float)tid * 0.20762050593046014f);  // 10000^(-d/64)

  const int KT = K >> 6;

  const floatx4 fzero = {0.f, 0.f, 0.f, 0.f};
  floatx4 acc[8][4];
#pragma unroll
  for (int i = 0; i < 8; ++i)
#pragma unroll
    for (int j = 0; j < 4; ++j) acc[i][j] = fzero;

  // ---- prologue: stage tile0 fully, drain, barrier ----
  {
    bf16* As0 = smem;
    bf16* Bs0 = smem + 16384;
    stage_half(As0, A, m0, 0, 0, K, w, l);
    stage_half(As0, A, m0, 0, 1, K, w, l);
    stage_half(Bs0, Bt, n0, 0, 0, K, w, l);
    stage_half(Bs0, Bt, n0, 0, 1, K, w, l);
    asm volatile("s_waitcnt vmcnt(0)" ::: "memory");
    __builtin_amdgcn_sched_barrier(0);
    __builtin_amdgcn_s_barrier();
    __builtin_amdgcn_sched_barrier(0);
  }

#pragma unroll 1
  for (int t = 0; t < KT; ++t) {
    const int cur = t & 1;
    bf16* As_c = smem + cur * 32768;
    bf16* Bs_c = As_c + 16384;
    bf16* As_n = smem + (cur ^ 1) * 32768;
    bf16* Bs_n = As_n + 16384;

    bf16x8 bfr[2][4];       // B frags live across all 4 phases
    bf16x8 af[2][2][2];     // [quad parity][mr][ks] — ping-pong, static idx after unroll

#pragma unroll
    for (int p = 0; p < 4; ++p) {
      if (p == 0) {
        // --- A-q0 frags ---
#pragma unroll
        for (int mr = 0; mr < 2; ++mr)
#pragma unroll
          for (int ks = 0; ks < 2; ++ks) {
            const int row = wm * 128 + mr * 16 + l16;
            const int slot = (ks * 4 + quad) ^ (row & 7);
            af[0][mr][ks] = *(const bf16x8*)(As_c + row * 64 + slot * 8);
          }
        // --- B frags (all 8) ---
#pragma unroll
        for (int ks = 0; ks < 2; ++ks)
#pragma unroll
          for (int ni = 0; ni < 4; ++ni) {
            const int row = wn * 64 + ni * 16 + l16;
            const int slot = (ks * 4 + quad) ^ (row & 7);
            bfr[ks][ni] = *(const bf16x8*)(Bs_c + row * 64 + slot * 8);
          }
        __builtin_amdgcn_sched_barrier(0);
        // --- A-q1 frags (last-issued: stay in flight past lgkm(4)) ---
#pragma unroll
        for (int mr = 0; mr < 2; ++mr)
#pragma unroll
          for (int ks = 0; ks < 2; ++ks) {
            const int row = wm * 128 + 32 + mr * 16 + l16;
            const int slot = (ks * 4 + quad) ^ (row & 7);
            af[1][mr][ks] = *(const bf16x8*)(As_c + row * 64 + slot * 8);
          }
        // --- stage t+1 B halves ---
        if (t + 1 < KT) {
          stage_half(Bs_n, Bt, n0, (t + 1) * 64, 0, K, w, l);
          stage_half(Bs_n, Bt, n0, (t + 1) * 64, 1, K, w, l);
        }
      } else if (p < 3) {
        // --- A-q(p+1) frags into the other parity slot ---
#pragma unroll
        for (int mr = 0; mr < 2; ++mr)
#pragma unroll
          for (int ks = 0; ks < 2; ++ks) {
            const int row = wm * 128 + (p + 1) * 32 + mr * 16 + l16;
            const int slot = (ks * 4 + quad) ^ (row & 7);
            af[(p + 1) & 1][mr][ks] = *(const bf16x8*)(As_c + row * 64 + slot * 8);
          }
        // --- stage t+1 A halves (in p1) ---
        if (p == 1 && t + 1 < KT) {
          stage_half(As_n, A, m0, (t + 1) * 64, 0, K, w, l);
          stage_half(As_n, A, m0, (t + 1) * 64, 1, K, w, l);
        }
      }

      __builtin_amdgcn_sched_barrier(0);
      __builtin_amdgcn_s_barrier();
      if (p < 3)
        asm volatile("s_waitcnt lgkmcnt(4)" ::: "memory");
      else
        asm volatile("s_waitcnt lgkmcnt(0)" ::: "memory");
      __builtin_amdgcn_sched_barrier(0);
      __builtin_amdgcn_s_setprio(1);
#pragma unroll
      for (int mr = 0; mr < 2; ++mr)
#pragma unroll
        for (int ks = 0; ks < 2; ++ks)
#pragma unroll
          for (int ni = 0; ni < 4; ++ni)
            acc[p * 2 + mr][ni] = __builtin_amdgcn_mfma_f32_16x16x32_bf16(
                af[p & 1][mr][ks], bfr[ks][ni], acc[p * 2 + mr][ni], 0, 0, 0);
      __builtin_amdgcn_s_setprio(0);
      if (p == 3) {
        // drain t+1's staging (issued >=2 phases ago) before anyone reads it
        asm volatile("s_waitcnt vmcnt(0)" ::: "memory");
        __builtin_amdgcn_sched_barrier(0);
      }
      __builtin_amdgcn_s_barrier();
    }
  }

  if constexpr (EPI == 0) {
    // C/D layout: col = lane&15, row = quad*4 + reg
#pragma unroll
    for (int mi = 0; mi < 8; ++mi)
#pragma unroll
      for (int ni = 0; ni < 4; ++ni) {
        const int row = m0 + wm * 128 + mi * 16 + quad * 4;
        const int col = n0 + wn * 64 + ni * 16 + l16;
#pragma unroll
        for (int r = 0; r < 4; ++r)
          C[(size_t)(row + r) * N + col] = (OutT)acc[mi][ni][r];
      }
  } else {
    // ---- fused epilogue: 2 rounds; round q stages quadrants (wm,q) of the
    //      256x256 tile as two 128x130 LDS tiles, then 256 threads/tile apply
    //      RoPE (Q/K cols) or transpose (V cols). All staging already drained.
    bf16* Tl = smem;
#pragma unroll 1
    for (int q = 0; q < 2; ++q) {
      if ((wn >> 1) == q) {
        bf16* Tg = Tl + wm * (128 * 130);
#pragma unroll
        for (int mi = 0; mi < 8; ++mi)
#pragma unroll
          for (int ni = 0; ni < 4; ++ni) {
            const int rl = mi * 16 + quad * 4;
            const int cl = (wn & 1) * 64 + ni * 16 + l16;
#pragma unroll
            for (int r = 0; r < 4; ++r)
              Tg[(rl + r) * 130 + cl] = (bf16)acc[mi][ni][r];
          }
      }
      __syncthreads();

      const int g = tid >> 8, t8 = tid & 255;      // group g handles quadrant (g,q)
      const int m0q = m0 + g * 128, n0q = n0 + q * 128;
      bf16* Tq = Tl + g * (128 * 130);
      const int nt = n0q >> 7;
      if (nt < 32) {
        // ---- Q or K quadrant: apply RoPE, store to qk[(m0q+r)][n0q + c] ----
        const int r = t8 >> 1, hd = t8 & 1;
        const float tt = (float)((m0q & (NT - 1)) + r);
        bf16* dst = qk + (size_t)(m0q + r) * QKS + n0q;
#pragma unroll
        for (int j8 = 0; j8 < 2; ++j8) {
          const int d0 = hd * 32 + j8 * 16;
          bf16x8 lo[2], hi[2];
#pragma unroll
          for (int half8 = 0; half8 < 2; ++half8) {
#pragma unroll
            for (int jj = 0; jj < 8; ++jj) {
              const int d = d0 + half8 * 8 + jj;
              const float x1 = (float)Tq[r * 130 + d];
              const float x2 = (float)Tq[r * 130 + d + 64];
              float s, c;
              __sincosf(tt * invf_s[d], &s, &c);
              lo[half8][jj] = (bf16)(x1 * c - x2 * s);
              hi[half8][jj] = (bf16)(x2 * c + x1 * s);
            }
            *(bf16x8*)(dst + d0 + half8 * 8) = lo[half8];
            *(bf16x8*)(dst + d0 + half8 * 8 + 64) = hi[half8];
          }
        }
      } else {
        // ---- V quadrant: transpose into vt[(b*16+h)*128 + d][t] ----
        const int h = nt - 32;
        const int b = m0q >> 11;          // quadrant never straddles batch
        const int t0 = m0q & (NT - 1);
        const int vbase = (b * NH + h) * ND;
#pragma unroll
        for (int ii = 0; ii < 8; ++ii) {
          const int dd = (t8 >> 4) + ii * 16;
          const int ch = t8 & 15;
          bf16x8 o;
#pragma unroll
          for (int j = 0; j < 8; ++j) o[j] = Tq[(ch * 8 + j) * 130 + dd];
          *(bf16x8*)(vt + (size_t)(vbase + dd) * NT + t0 + ch * 8) = o;
        }
      }
      __syncthreads();
    }
  }
}

// ------------- flash attention: 32x32 MFMA, S^T/O^T orientation,
//               double-buffered K/V LDS, paired q-tiles for load balance.
//   This round: (1) XCD-coherent 1D grid decode — all 8 pair-blocks of one
//   (b,h) share id mod 8 -> same XCD, K/V panel (512KB) stays L2-resident;
//   (2) defer-max (T13, THR=8 in log2 domain) skips the O-rescale pass when
//   the running max grows < 2^8; (3) s_setprio(1) around both MFMA clusters
//   (m191: +4-7% on attn's independent-wave regime).
__global__ __launch_bounds__(256) void attn_kernel(const bf16* __restrict__ qk,
                                                   const bf16* __restrict__ vt,
                                                   bf16* __restrict__ y) {
  __shared__ bf16 Ks[2][64 * 128];   // [buf][kv][d]  xor-swizzled 16B chunks
  __shared__ bf16 Vs[2][128 * 64];   // [buf][d][kv]  xor-swizzled 16B chunks

  // XCD-coherent decode: id = c + 8*(pair + 8*hbhi); hb = hbhi*8 + c.
  const int id = blockIdx.x;
  const int c8 = id & 7, rest = id >> 3;
  const int pair = rest & 7, hbhi = rest >> 3;
  const int hb = hbhi * 8 + c8;
  const int h = hb & 15, b = hb >> 4;

  const int tid = threadIdx.x;
  const int w = tid >> 6, l = tid & 63, half = l >> 5, l32 = l & 31;
  const float SCL = 0.08838834764831845f * 1.4426950408889634f;  // 1/sqrt(128)*log2(e)

#pragma unroll 1
  for (int pi = 0; pi < 2; ++pi) {
    const int qt = pi ? (15 - pair) : pair;
    const int q0 = qt * 128;
    const int ntiles = qt * 2 + 2;
    const int qg = q0 + w * 32 + l32;   // this lane's q row

    // Q B-fragments from global (RoPE'd): Q[q=l32][d = ks*16 + half*8 + j]
    bf16x8 aq[8];
#pragma unroll
    for (int ks = 0; ks < 8; ++ks)
      aq[ks] = *(const bf16x8*)(qk + (size_t)(b * NT + qg) * QKS + h * ND + ks * 16 + half * 8);

    floatx16 acc[4];
#pragma unroll
    for (int ni = 0; ni < 4; ++ni)
#pragma unroll
      for (int r = 0; r < 16; ++r) acc[ni][r] = 0.f;
    float mold = -3.0e38f, lsum = 0.f;

    // ---- stage tile 0 into buffer 0 ----
    {
#pragma unroll
      for (int i = 0; i < 4; ++i) {
        const int fb = i * 256 + w * 64, f = fb + l;
        { const int r = f >> 4, cs = f & 15, c = cs ^ (r & 15);
          load_lds16(qk + (size_t)(b * NT + r) * QKS + NC + h * ND + c * 8, &Ks[0][fb * 8]); }
        { const int r = f >> 3, cs = f & 7, c = cs ^ (r & 7);
          load_lds16(vt + ((size_t)((b * NH + h) * ND + r)) * NT + c * 8, &Vs[0][fb * 8]); }
      }
    }

#pragma unroll 1
    for (int it = 0; it < ntiles; ++it) {
      const int kv0 = it * 64;
      const int buf = it & 1;
      __syncthreads();   // drains loads for tile it; all waves done reading buf^1

      if (it + 1 < ntiles) {  // prefetch tile it+1 into the other buffer
        const int kvn = kv0 + 64, nb = buf ^ 1;
#pragma unroll
        for (int i = 0; i < 4; ++i) {
          const int fb = i * 256 + w * 64, f = fb + l;
          { const int r = f >> 4, cs = f & 15, c = cs ^ (r & 15);
            load_lds16(qk + (size_t)(b * NT + kvn + r) * QKS + NC + h * ND + c * 8, &Ks[nb][fb * 8]); }
          { const int r = f >> 3, cs = f & 7, c = cs ^ (r & 7);
            load_lds16(vt + ((size_t)((b * NH + h) * ND + r)) * NT + kvn + c * 8, &Vs[nb][fb * 8]); }
        }
      }

      if (kv0 <= q0 + w * 32 + 31) {  // wave has at least one unmasked kv
        // ---- S^T = K Q^T  (C: kv = (r&3)+8*(r>>2)+4*half, q = l32) ----
        floatx16 st[2];
#pragma unroll
        for (int ki = 0; ki < 2; ++ki)
#pragma unroll
          for (int r = 0; r < 16; ++r) st[ki][r] = 0.f;
        __builtin_amdgcn_s_setprio(1);
#pragma unroll
        for (int ks = 0; ks < 8; ++ks) {
          const int slot = (ks * 2 + half) ^ (l32 & 15);
#pragma unroll
          for (int ki = 0; ki < 2; ++ki) {
            const bf16x8 ak = *(const bf16x8*)(&Ks[buf][(ki * 32 + l32) * 128 + slot * 8]);
            st[ki] = __builtin_amdgcn_mfma_f32_32x32x16_bf16(ak, aq[ks], st[ki], 0, 0, 0);
          }
        }
        __builtin_amdgcn_s_setprio(0);

        // ---- mask + scale + row max (in-lane 32 + one shfl) ----
        float mx = -3.0e38f;
        if (kv0 + 63 > q0 + w * 32) {
#pragma unroll
          for (int ki = 0; ki < 2; ++ki)
#pragma unroll
            for (int r = 0; r < 16; ++r) {
              const int kg = kv0 + ki * 32 + (r & 3) + 8 * (r >> 2) + 4 * half;
              float s = st[ki][r] * SCL;
              s = (kg > qg) ? -3.0e38f : s;
              st[ki][r] = s;
              mx = fmaxf(mx, s);
            }
        } else {
#pragma unroll
          for (int ki = 0; ki < 2; ++ki)
#pragma unroll
            for (int r = 0; r < 16; ++r) {
              const float s = st[ki][r] * SCL;
              st[ki][r] = s;
              mx = fmaxf(mx, s);
            }
        }
        mx = fmaxf(mx, __shfl_xor(mx, 32));

        // ---- online softmax (log2 domain), defer-max (T13, THR=8) ----
        // Rescale only when some row's max grew by >2^8; otherwise keep mold
        // (P bounded by 2^8 — f32 lsum and bf16 P precision are scale-inv).
        if (!__all(mx - mold <= 8.f)) {
          const float mnew = fmaxf(mold, mx);
          const float al = exp2f(mold - mnew);
          lsum *= al;
#pragma unroll
          for (int ni = 0; ni < 4; ++ni)
#pragma unroll
            for (int r = 0; r < 16; ++r) acc[ni][r] *= al;
          mold = mnew;
        }
        float rs = 0.f;
#pragma unroll
        for (int ki = 0; ki < 2; ++ki)
#pragma unroll
          for (int r = 0; r < 16; ++r) {
            const float p = exp2f(st[ki][r] - mold);
            st[ki][r] = p;
            rs += p;
          }
        rs += __shfl_xor(rs, 32);
        lsum += rs;

        // ---- repack P (C-layout) -> B-operand, in-register (16 shfl_xor32) ----
        unsigned pk[2][8];
#pragma unroll
        for (int ki = 0; ki < 2; ++ki)
#pragma unroll
          for (int d = 0; d < 8; ++d)
            pk[ki][d] = pack2(st[ki][2 * d], st[ki][2 * d + 1]);
        bf16x8 bp[4];
#pragma unroll
        for (int s = 0; s < 4; ++s) {
          const int ki = s >> 1, o = (s & 1) * 4;
          const unsigned a0 = pk[ki][o], a1 = pk[ki][o + 1], a2 = pk[ki][o + 2], a3 = pk[ki][o + 3];
          const unsigned s0 = (unsigned)__shfl_xor((int)a0, 32);
          const unsigned s1 = (unsigned)__shfl_xor((int)a1, 32);
          const unsigned s2 = (unsigned)__shfl_xor((int)a2, 32);
          const unsigned s3 = (unsigned)__shfl_xor((int)a3, 32);
          uint4 dw;
          dw.x = half ? s2 : a0;
          dw.y = half ? s3 : a1;
          dw.z = half ? a2 : s0;
          dw.w = half ? a3 : s1;
          bp[s] = __builtin_bit_cast(bf16x8, dw);
        }

        // ---- O^T += V^T P^T  (A = V^T rows, B = P) ----
        __builtin_amdgcn_s_setprio(1);
#pragma unroll
        for (int ni = 0; ni < 4; ++ni) {
          const int rv = ni * 32 + l32;
#pragma unroll
          for (int s = 0; s < 4; ++s) {
            const int slot = (s * 2 + half) ^ (l32 & 7);
            const bf16x8 av = *(const bf16x8*)(&Vs[buf][rv * 64 + slot * 8]);
            acc[ni] = __builtin_amdgcn_mfma_f32_32x32x16_bf16(av, bp[s], acc[ni], 0, 0, 0);
          }
        }
        __builtin_amdgcn_s_setprio(0);
      }
    }

    // ---- epilogue: O^T lane holds (d = ni*32+8*rg+4*half+j, q = l32) ----
    const float inv = 1.f / lsum;
    const size_t orow = (size_t)(b * NT + qg) * NC + h * ND;
#pragma unroll
    for (int ni = 0; ni < 4; ++ni)
#pragma unroll
      for (int rg = 0; rg < 4; ++rg) {
        bf16x4 o;
#pragma unroll
        for (int j = 0; j < 4; ++j) o[j] = (bf16)(acc[ni][rg * 4 + j] * inv);
        *(bf16x4*)(y + orow + ni * 32 + rg * 8 + half * 4) = o;
      }
    __syncthreads();  // protect K/V buffers before next sub-tile overwrites
  }
}

extern "C" void kernel_launch(void* const* d_in, const int* in_sizes, int n_in,
                              void* d_out, int out_size, void* d_ws, size_t ws_size,
                              hipStream_t stream) {
  const float* x      = (const float*)d_in[0];  // (4,2048,2048)
  const float* w_attn = (const float*)d_in[1];  // (2048,6144)
  const float* w_proj = (const float*)d_in[2];  // (2048,2048)
  float* out = (float*)d_out;
  char* ws = (char*)d_ws;

  // workspace layout: total 176,160,768 B (same proven footprint)
  bf16* qk  = (bf16*)(ws);                 // [8192][4096] RoPE'd Q|K   67,108,864 B
  bf16* vt  = (bf16*)(ws + 67108864);      // [4*16*128][2048] V^T      33,554,432 B
  bf16* xb  = (bf16*)(ws + 100663296);     // [8192][2048]              33,554,432 B
  bf16* wab = (bf16*)(ws + 134217728);     // [6144][2048]              25,165,824 B
  bf16* y   = wab;                         // aliases wab (dead after GEMM1)
  bf16* wpb = (bf16*)(ws + 167772160);     // [2048][2048]               8,388,608 B

  cast_f32_bf16<<<dim3(16384), dim3(256), 0, stream>>>(x, xb);
  transpose_cast<<<dim3(96, 16), dim3(256), 0, stream>>>(w_attn, wab, 2048, 6144);
  transpose_cast<<<dim3(32, 16), dim3(256), 0, stream>>>(w_proj, wpb, 2048, 2048);
  gemm_bt<1, float><<<dim3(768), dim3(512), 0, stream>>>(xb, wab, (float*)nullptr, qk, vt,
                                                         8192, 6144, 2048, 24);
  attn_kernel<<<dim3(512), dim3(256), 0, stream>>>(qk, vt, y);
  gemm_bt<0, float><<<dim3(256), dim3(512), 0, stream>>>(y, wpb, out, nullptr, nullptr,
                                                         8192, 2048, 2048, 8);
}